// Round 1
// baseline (33.132 us; speedup 1.0000x reference)
//
#include <hip/hip_runtime.h>

// TransformLayer: per-pixel reprojection, B=8 H=768 W=1024, fp32.
// Memory-bound: 25.2 MB read + 100.7 MB write -> ~20 us roofline.

#define EPSF 1e-06f

constexpr int Bc = 8;
constexpr int Hc = 768;
constexpr int Wc = 1024;
constexpr int HW = Hc * Wc;          // 786432
constexpr int THREADS = 256;
constexpr int PIX_PER_THREAD = 4;    // float4 I/O
constexpr int BLOCKS_X = HW / (THREADS * PIX_PER_THREAD); // 768

__global__ __launch_bounds__(THREADS)
void transform_layer_kernel(const float* __restrict__ inv_depth,
                            const float* __restrict__ transform,
                            const float* __restrict__ calib_i,
                            const float* __restrict__ lam_i_p,
                            const float* __restrict__ calib_j,
                            const float* __restrict__ lam_j_p,
                            float* __restrict__ out)
{
#pragma clang fp contract(off)
    const int b    = blockIdx.y;                        // batch (wave-uniform)
    const int g4   = blockIdx.x * THREADS + threadIdx.x; // 4-pixel group index
    const int p0   = g4 * PIX_PER_THREAD;               // first pixel in group
    const int yrow = p0 >> 10;                          // p0 / W
    const int x0   = p0 & (Wc - 1);                     // p0 % W  (same row for all 4)

    // Per-batch params (uniform addresses -> scalar loads)
    const float* T = transform + b * 16;
    const float t00=T[0], t01=T[1], t02=T[2], t03=T[3];
    const float t10=T[4], t11=T[5], t12=T[6], t13=T[7];
    const float t20=T[8], t21=T[9], t22=T[10], t23=T[11];
    const float t30=T[12], t31=T[13], t32=T[14], t33=T[15];
    const float fx  = calib_i[b*4+0], fy  = calib_i[b*4+1];
    const float cx  = calib_i[b*4+2], cy  = calib_i[b*4+3];
    const float li  = lam_i_p[b];
    const float fxj = calib_j[b*4+0], fyj = calib_j[b*4+1];
    const float cxj = calib_j[b*4+2], cyj = calib_j[b*4+3];
    const float lj  = lam_j_p[b];

    // Vectorized input load: 4 consecutive inv_depth values
    const float4 idv = reinterpret_cast<const float4*>(inv_depth + (size_t)b * HW)[g4];
    const float id[4] = { idv.x, idv.y, idv.z, idv.w };

    float u4[4], v4[4], rho4[4], m4[4];

    const float yy = (float)yrow;
    const float yn = (yy - cy) / fy;   // same for all 4 pixels of the row

#pragma unroll
    for (int i = 0; i < 4; ++i) {
        const float xx = (float)(x0 + i);
        // undistort (division model, camera i)
        const float xn = (xx - cx) / fx;
        const float r2 = xn * xn + yn * yn;
        const float den = 1.0f + li * r2;
        const bool valid_norm = den > EPSF;
        const float den_s = valid_norm ? den : 1.0f;
        const float X0 = xn / den_s;
        const float X1 = yn / den_s;
        const float X3 = id[i];
        // rigid 4x4 transform (X2 == 1)
        const float a  = ((t00 * X0 + t01 * X1) + t02) + t03 * X3;
        const float bb = ((t10 * X0 + t11 * X1) + t12) + t13 * X3;
        const float c  = ((t20 * X0 + t21 * X1) + t22) + t23 * X3;
        const float d  = ((t30 * X0 + t31 * X1) + t32) + t33 * X3;
        // perspective divide
        const bool mask_src = c > EPSF;
        const float cz = mask_src ? c : 1.0f;
        const float xp = a / cz;
        const float yp = bb / cz;
        const float rho = d / cz;
        // redistort (division model, camera j)
        const float ru2 = xp * xp + yp * yp;
        const float disc = 1.0f - (4.0f * lj) * ru2;
        const bool valid_un = disc >= 0.0f;
        const float den2 = (2.0f * lj) * ru2;
        const bool use_ratio = valid_un && (fabsf(den2) > EPSF);
        const float sqrt_disc = sqrtf(disc > 0.0f ? disc : 1.0f);
        const float ratio = use_ratio ? (1.0f - sqrt_disc) / den2 : 1.0f;
        const float xd = xp * ratio;
        const float yd = yp * ratio;
        // project (camera j)
        const float u = fxj * xd + cxj;
        const float v = fyj * yd + cyj;
        const bool inb = (u >= 0.0f) & (u <= (float)(Wc - 1)) &
                         (v >= 0.0f) & (v <= (float)(Hc - 1));
        const bool mask = mask_src & inb & valid_norm & valid_un;

        u4[i] = u; v4[i] = v; rho4[i] = rho;
        m4[i] = mask ? 1.0f : 0.0f;
    }

    // Coalesced float4 stores: 3 x_proj planes + mask plane
    float* up = out + (size_t)b * 3 * HW + p0;
    *reinterpret_cast<float4*>(up)            = make_float4(u4[0], u4[1], u4[2], u4[3]);
    *reinterpret_cast<float4*>(up + HW)       = make_float4(v4[0], v4[1], v4[2], v4[3]);
    *reinterpret_cast<float4*>(up + 2 * HW)   = make_float4(rho4[0], rho4[1], rho4[2], rho4[3]);
    float* mp = out + (size_t)Bc * 3 * HW + (size_t)b * HW + p0;
    *reinterpret_cast<float4*>(mp)            = make_float4(m4[0], m4[1], m4[2], m4[3]);
}

extern "C" void kernel_launch(void* const* d_in, const int* in_sizes, int n_in,
                              void* d_out, int out_size, void* d_ws, size_t ws_size,
                              hipStream_t stream) {
    const float* inv_depth = (const float*)d_in[0];
    const float* transform = (const float*)d_in[1];
    const float* calib_i   = (const float*)d_in[2];
    const float* lam_i     = (const float*)d_in[3];
    const float* calib_j   = (const float*)d_in[4];
    const float* lam_j     = (const float*)d_in[5];
    // d_in[6] = non_rigid, always 0 for this problem (rigid einsum path)
    float* out = (float*)d_out;

    dim3 grid(BLOCKS_X, Bc);
    dim3 block(THREADS);
    transform_layer_kernel<<<grid, block, 0, stream>>>(
        inv_depth, transform, calib_i, lam_i, calib_j, lam_j, out);
}

// Round 2
// 25.232 us; speedup vs baseline: 1.3131x; 1.3131x over previous
//
#include <hip/hip_runtime.h>

// TransformLayer: per-pixel reprojection, B=8 H=768 W=1024, fp32.
// Memory-bound target: 25.2 MB read + 100.7 MB write -> ~19 us at fill-kernel BW.
// R1: replace IEEE div/sqrt with v_rcp_f32/v_sqrt_f32 (+FMA contraction) to cut
//     per-pixel VALU ~4x. Value threshold is 23.04 -> 1-2 ulp deviation is safe.

#define EPSF 1e-06f

constexpr int Bc = 8;
constexpr int Hc = 768;
constexpr int Wc = 1024;
constexpr int HW = Hc * Wc;          // 786432
constexpr int THREADS = 256;
constexpr int PIX_PER_THREAD = 4;    // float4 I/O
constexpr int BLOCKS_X = HW / (THREADS * PIX_PER_THREAD); // 768

__device__ __forceinline__ float frcp(float x)  { return __builtin_amdgcn_rcpf(x); }
__device__ __forceinline__ float fsqrtf_(float x){ return __builtin_amdgcn_sqrtf(x); }

__global__ __launch_bounds__(THREADS)
void transform_layer_kernel(const float* __restrict__ inv_depth,
                            const float* __restrict__ transform,
                            const float* __restrict__ calib_i,
                            const float* __restrict__ lam_i_p,
                            const float* __restrict__ calib_j,
                            const float* __restrict__ lam_j_p,
                            float* __restrict__ out)
{
    const int b    = blockIdx.y;                         // batch (wave-uniform)
    const int g4   = blockIdx.x * THREADS + threadIdx.x; // 4-pixel group index
    const int p0   = g4 * PIX_PER_THREAD;                // first pixel in group
    const int yrow = p0 >> 10;                           // p0 / W
    const int x0   = p0 & (Wc - 1);                      // p0 % W (same row for all 4)

    // Per-batch params (uniform addresses -> scalar loads)
    const float* T = transform + b * 16;
    const float t00=T[0], t01=T[1], t02=T[2], t03=T[3];
    const float t10=T[4], t11=T[5], t12=T[6], t13=T[7];
    const float t20=T[8], t21=T[9], t22=T[10], t23=T[11];
    const float t30=T[12], t31=T[13], t32=T[14], t33=T[15];
    const float fx  = calib_i[b*4+0], fy  = calib_i[b*4+1];
    const float cx  = calib_i[b*4+2], cy  = calib_i[b*4+3];
    const float li  = lam_i_p[b];
    const float fxj = calib_j[b*4+0], fyj = calib_j[b*4+1];
    const float cxj = calib_j[b*4+2], cyj = calib_j[b*4+3];
    const float lj  = lam_j_p[b];
    const float lj4 = 4.0f * lj;
    const float lj2 = 2.0f * lj;

    const float rfx = frcp(fx);            // hoisted reciprocals (uniform values)
    const float rfy = frcp(fy);

    // Vectorized input load: 4 consecutive inv_depth values
    const float4 idv = reinterpret_cast<const float4*>(inv_depth + (size_t)b * HW)[g4];
    const float id[4] = { idv.x, idv.y, idv.z, idv.w };

    float u4[4], v4[4], rho4[4], m4[4];

    const float yn = ((float)yrow - cy) * rfy;   // same for all 4 pixels of the row
    const float yn2 = yn * yn;

#pragma unroll
    for (int i = 0; i < 4; ++i) {
        const float xx = (float)(x0 + i);
        // undistort (division model, camera i)
        const float xn = (xx - cx) * rfx;
        const float r2 = xn * xn + yn2;
        const float den = 1.0f + li * r2;
        const bool valid_norm = den > EPSF;
        const float rden = frcp(valid_norm ? den : 1.0f);
        const float X0 = xn * rden;
        const float X1 = yn * rden;
        const float X3 = id[i];
        // rigid 4x4 transform (X2 == 1)
        const float a  = ((t00 * X0 + t01 * X1) + t02) + t03 * X3;
        const float bb = ((t10 * X0 + t11 * X1) + t12) + t13 * X3;
        const float c  = ((t20 * X0 + t21 * X1) + t22) + t23 * X3;
        const float d  = ((t30 * X0 + t31 * X1) + t32) + t33 * X3;
        // perspective divide
        const bool mask_src = c > EPSF;
        const float rcz = frcp(mask_src ? c : 1.0f);
        const float xp = a * rcz;
        const float yp = bb * rcz;
        const float rho = d * rcz;
        // redistort (division model, camera j)
        const float ru2 = xp * xp + yp * yp;
        const float disc = 1.0f - lj4 * ru2;
        const bool valid_un = disc >= 0.0f;
        const float den2 = lj2 * ru2;
        const bool use_ratio = valid_un && (fabsf(den2) > EPSF);
        const float sqrt_disc = fsqrtf_(disc > 0.0f ? disc : 1.0f);
        const float ratio = use_ratio ? (1.0f - sqrt_disc) * frcp(den2) : 1.0f;
        const float xd = xp * ratio;
        const float yd = yp * ratio;
        // project (camera j)
        const float u = fxj * xd + cxj;
        const float v = fyj * yd + cyj;
        const bool inb = (u >= 0.0f) & (u <= (float)(Wc - 1)) &
                         (v >= 0.0f) & (v <= (float)(Hc - 1));
        const bool mask = mask_src & inb & valid_norm & valid_un;

        u4[i] = u; v4[i] = v; rho4[i] = rho;
        m4[i] = mask ? 1.0f : 0.0f;
    }

    // Coalesced float4 stores: 3 x_proj planes + mask plane
    float* up = out + (size_t)b * 3 * HW + p0;
    *reinterpret_cast<float4*>(up)            = make_float4(u4[0], u4[1], u4[2], u4[3]);
    *reinterpret_cast<float4*>(up + HW)       = make_float4(v4[0], v4[1], v4[2], v4[3]);
    *reinterpret_cast<float4*>(up + 2 * HW)   = make_float4(rho4[0], rho4[1], rho4[2], rho4[3]);
    float* mp = out + (size_t)Bc * 3 * HW + (size_t)b * HW + p0;
    *reinterpret_cast<float4*>(mp)            = make_float4(m4[0], m4[1], m4[2], m4[3]);
}

extern "C" void kernel_launch(void* const* d_in, const int* in_sizes, int n_in,
                              void* d_out, int out_size, void* d_ws, size_t ws_size,
                              hipStream_t stream) {
    const float* inv_depth = (const float*)d_in[0];
    const float* transform = (const float*)d_in[1];
    const float* calib_i   = (const float*)d_in[2];
    const float* lam_i     = (const float*)d_in[3];
    const float* calib_j   = (const float*)d_in[4];
    const float* lam_j     = (const float*)d_in[5];
    // d_in[6] = non_rigid, always 0 for this problem (rigid einsum path)
    float* out = (float*)d_out;

    dim3 grid(BLOCKS_X, Bc);
    dim3 block(THREADS);
    transform_layer_kernel<<<grid, block, 0, stream>>>(
        inv_depth, transform, calib_i, lam_i, calib_j, lam_j, out);
}